// Round 5
// baseline (1015.577 us; speedup 1.0000x reference)
//
#include <hip/hip_runtime.h>
#include <hip/hip_bf16.h>

// Problem constants (fixed by the reference):
//   N=100000, E=500000, V=50000, NE=1000000, D=300, C=20, NG=512
#define NG 512
#define D_DIM 300
#define C_DIM 20
#define K3_EPB 2048
#define CH 256

// ---- SpMM-by-vocab parameters ----
#define VCAP 128      // max (g,s) pairs kept per vocab row (max observed degree ~75)
#define SLICES 10     // ceil(300/32) dim-slices of 32
#define VCHUNK 1000   // vocab rows per block

// ---------------- K1: in-degree ----------------
__global__ __launch_bounds__(256) void fb_count(const int* __restrict__ dst, int* __restrict__ cnt, int E) {
    for (int e = blockIdx.x * 256 + threadIdx.x; e < E; e += gridDim.x * 256)
        atomicAdd(&cnt[dst[e]], 1);
}

// ---------------- K2: bucketed counting-scatter by vocab row ----------------
// bucket[v][pos] = (g, s) for each edge with source-word v.
__global__ __launch_bounds__(256) void bucket_build(const int* __restrict__ src,
                                                    const int* __restrict__ dst,
                                                    const int* __restrict__ eb,
                                                    const int* __restrict__ nodes_batch,
                                                    const float* __restrict__ edge_embed,
                                                    const int* __restrict__ graph_ids,
                                                    const int* __restrict__ cnt,
                                                    int* __restrict__ vdeg,
                                                    int2* __restrict__ bucket, int E) {
    for (int e = blockIdx.x * 256 + threadIdx.x; e < E; e += gridDim.x * 256) {
        int d = dst[e];
        int v = nodes_batch[src[e]];
        float s = edge_embed[eb[e]] / (float)max(cnt[d], 1);
        int pos = atomicAdd(&vdeg[v], 1);
        if (pos < VCAP)
            bucket[(size_t)v * VCAP + pos] = make_int2(graph_ids[d], __float_as_int(s));
    }
}

// ---------------- K3: SpMM — stream B rows, accumulate gacc slice in LDS ----------------
// Block = (slice, v-chunk). LDS acc[512 graphs][32 dims] (64KB, 2 blocks/CU).
// Wave handles 2 vocab rows at a time (half-wave = 32 lanes = 32 dims).
__global__ __launch_bounds__(512, 2) void spmm_kernel(const int2* __restrict__ bucket,
                                                      const int* __restrict__ vdeg,
                                                      const float* __restrict__ Bmat,
                                                      float* __restrict__ gacc,
                                                      int K, int nvch) {
    __shared__ float acc[NG * 32];   // 64 KB exactly
    int bid = blockIdx.x;
    int slice = bid % SLICES;
    int vch = bid / SLICES;
    int d0 = slice * 32;
    int t = threadIdx.x;

    for (int i = t; i < NG * 32; i += 512) acc[i] = 0.f;
    __syncthreads();

    int v0 = vch * VCHUNK;
    int v1 = min(v0 + VCHUNK, K);
    int wv = t >> 6;                 // wave 0..7
    int half = (t & 63) >> 5;        // 0/1: which vocab row of this wave
    int lane31 = t & 31;             // dim within slice
    int d = d0 + lane31;
    bool dok = d < D_DIM;

    for (int v = v0 + wv * 2 + half; v < v1; v += 16) {
        int deg = min(vdeg[v], VCAP);
        if (deg == 0) continue;
        float bval = dok ? Bmat[(size_t)v * D_DIM + d] : 0.f;
        const int2* bk = bucket + (size_t)v * VCAP;
        for (int b0 = 0; b0 < deg; b0 += 32) {
            int nb = min(32, deg - b0);
            int2 pr = bk[b0 + (lane31 < nb ? lane31 : 0)];
            for (int j = 0; j < nb; j++) {
                int g = __shfl(pr.x, j, 32);
                float s = __shfl(__int_as_float(pr.y), j, 32);
                atomicAdd(&acc[g * 32 + lane31], s * bval);
            }
        }
    }
    __syncthreads();
    // flush: f = k*512+t -> (g = f>>5, i = f&31): consecutive t = consecutive banks
    for (int k = 0; k < 32; k++) {
        int f = k * 512 + t;
        int g = f >> 5;
        int i = f & 31;
        int dd = d0 + i;
        float val = acc[f];
        if (dd < D_DIM && val != 0.f)
            atomicAdd(&gacc[g * D_DIM + dd], val);
    }
}

// ---------------- K4: per-graph ReLU + FC ----------------
__global__ __launch_bounds__(320) void fc_kernel(const float* __restrict__ gacc,
                                                 const float* __restrict__ fc_w,
                                                 const float* __restrict__ fc_b,
                                                 float* __restrict__ out) {
    __shared__ float wlds[D_DIM * C_DIM];
    __shared__ float accs[D_DIM];
    __shared__ float outs[C_DIM];
    int gid = blockIdx.x;
    int t = threadIdx.x;
    for (int i = t; i < D_DIM * C_DIM; i += 320) wlds[i] = fc_w[i];
    if (t < D_DIM) accs[t] = gacc[gid * D_DIM + t];
    if (t < C_DIM) outs[t] = fc_b[t];
    __syncthreads();
    if (t < C_DIM * 12) {
        int c = t % C_DIM;
        int ch = t / C_DIM;
        float p = 0.f;
#pragma unroll
        for (int d = ch * 25; d < ch * 25 + 25; d++) {
            float gv = accs[d];
            gv = gv > 0.f ? gv : 0.f;
            p += gv * wlds[d * C_DIM + c];
        }
        atomicAdd(&outs[c], p);
    }
    __syncthreads();
    if (t < C_DIM) out[gid * C_DIM + t] = outs[t];
}

// ================= fallback path (R3 structure, small ws) =================
__global__ __launch_bounds__(256) void count_kernel(const int* __restrict__ dst,
                                                    const int* __restrict__ graph_ids,
                                                    int* __restrict__ cnt,
                                                    int* __restrict__ gcnt, int E) {
    __shared__ int lg[NG];
    int t = threadIdx.x;
    for (int i = t; i < NG; i += 256) lg[i] = 0;
    __syncthreads();
    for (int e = blockIdx.x * 256 + t; e < E; e += gridDim.x * 256) {
        int d = dst[e];
        atomicAdd(&cnt[d], 1);
        atomicAdd(&lg[graph_ids[d]], 1);
    }
    __syncthreads();
    for (int i = t; i < NG; i += 256)
        if (lg[i]) atomicAdd(&gcnt[i], lg[i]);
}

__global__ __launch_bounds__(NG) void scan_kernel(const int* __restrict__ gcnt,
                                                  int* __restrict__ goff,
                                                  int* __restrict__ gfill) {
    __shared__ int s[NG];
    int t = threadIdx.x;
    int v = gcnt[t];
    s[t] = v;
    __syncthreads();
    for (int off = 1; off < NG; off <<= 1) {
        int x = (t >= off) ? s[t - off] : 0;
        __syncthreads();
        s[t] += x;
        __syncthreads();
    }
    int excl = s[t] - v;
    goff[t] = excl;
    gfill[t] = excl;
}

__global__ __launch_bounds__(256) void scatter_kernel(const int* __restrict__ src,
                                                      const int* __restrict__ dst,
                                                      const int* __restrict__ eb,
                                                      const int* __restrict__ nodes_batch,
                                                      const float* __restrict__ edge_embed,
                                                      const int* __restrict__ graph_ids,
                                                      const int* __restrict__ cnt,
                                                      int* __restrict__ gfill,
                                                      int2* __restrict__ elist, int E) {
    __shared__ int bcnt[NG];
    __shared__ int base[NG];
    int t = threadIdx.x;
    int e0 = blockIdx.x * K3_EPB;
    for (int i = t; i < NG; i += 256) bcnt[i] = 0;
    __syncthreads();
    int rows[K3_EPB / 256];
    float scales[K3_EPB / 256];
    int gids[K3_EPB / 256];
#pragma unroll
    for (int k = 0; k < K3_EPB / 256; k++) {
        int e = e0 + k * 256 + t;
        gids[k] = -1;
        if (e < E) {
            int d = dst[e];
            int g = graph_ids[d];
            gids[k] = g;
            rows[k] = nodes_batch[src[e]];
            scales[k] = edge_embed[eb[e]] / (float)max(cnt[d], 1);
            atomicAdd(&bcnt[g], 1);
        }
    }
    __syncthreads();
    for (int i = t; i < NG; i += 256) {
        int c2 = bcnt[i];
        base[i] = c2 ? atomicAdd(&gfill[i], c2) : 0;
        bcnt[i] = 0;
    }
    __syncthreads();
#pragma unroll
    for (int k = 0; k < K3_EPB / 256; k++) {
        int g = gids[k];
        if (g >= 0) {
            int pos = base[g] + atomicAdd(&bcnt[g], 1);
            elist[pos] = make_int2(rows[k], __float_as_int(scales[k]));
        }
    }
}

__global__ __launch_bounds__(320) void accum_kernel(const int2* __restrict__ elist,
                                                    const int* __restrict__ goff,
                                                    const float* __restrict__ node_embed,
                                                    float* __restrict__ gacc, int E) {
    __shared__ int2 tile[CH];
    __shared__ int goff_s[NG + 1];
    int t = threadIdx.x;
    int sub = t / 80;
    int lane = t % 80;
    int d0 = lane * 4;
    bool act = d0 < D_DIM;
    int pos0 = blockIdx.x * CH;
    int m = min(CH, E - pos0);
    for (int i = t; i < NG; i += 320) goff_s[i] = goff[i];
    if (t == 0) goff_s[NG] = E;
    for (int i = t; i < m; i += 320) tile[i] = elist[pos0 + i];
    __syncthreads();
    int lo = 0, hi = NG - 1;
    while (lo < hi) {
        int mid = (lo + hi + 1) >> 1;
        if (goff_s[mid] <= pos0) lo = mid; else hi = mid - 1;
    }
    int g = lo;
    int j = 0;
    while (j < m) {
        while (pos0 + j >= goff_s[g + 1]) g++;
        int end = min(m, goff_s[g + 1] - pos0);
        float ax = 0.f, ay = 0.f, az = 0.f, aw = 0.f;
        if (act) {
#pragma unroll 8
            for (int jj = j + sub; jj < end; jj += 4) {
                int2 pr = tile[jj];
                float s = __int_as_float(pr.y);
                const float4* rowp = (const float4*)(node_embed + (size_t)pr.x * D_DIM);
                float4 vv = rowp[lane];
                ax += s * vv.x; ay += s * vv.y; az += s * vv.z; aw += s * vv.w;
            }
            float* dest = gacc + g * D_DIM + d0;
            atomicAdd(dest + 0, ax);
            atomicAdd(dest + 1, ay);
            atomicAdd(dest + 2, az);
            atomicAdd(dest + 3, aw);
        }
        j = end;
    }
}

extern "C" void kernel_launch(void* const* d_in, const int* in_sizes, int n_in,
                              void* d_out, int out_size, void* d_ws, size_t ws_size,
                              hipStream_t stream) {
    const int* nodes_batch = (const int*)d_in[0];
    const int* edges_batch = (const int*)d_in[1];
    const int* src = (const int*)d_in[2];
    const int* dst = (const int*)d_in[3];
    const int* graph_ids = (const int*)d_in[4];
    const float* node_embed = (const float*)d_in[5];
    const float* edge_embed = (const float*)d_in[6];
    const float* fc_w = (const float*)d_in[7];
    const float* fc_b = (const float*)d_in[8];
    float* out = (float*)d_out;

    int N = in_sizes[0];
    int E = in_sizes[2];
    int K = in_sizes[5] / D_DIM;   // vocab size V

    char* ws = (char*)d_ws;
    size_t off = 0;
    int* cnt = (int*)(ws + off); off += (size_t)N * 4;
    int* gcnt = (int*)(ws + off); off += NG * 4;
    int* goff = (int*)(ws + off); off += NG * 4;
    int* gfill = (int*)(ws + off); off += NG * 4;
    int* vdeg = (int*)(ws + off); off += (size_t)K * 4;
    float* gacc = (float*)(ws + off); off += (size_t)NG * D_DIM * 4;
    off = (off + 15) & ~(size_t)15;
    size_t need_main = off + (size_t)K * VCAP * 8;
    size_t need_fb = off + (size_t)E * 8;

    if (ws_size >= need_main) {
        int2* bucket = (int2*)(ws + off);
        hipMemsetAsync(cnt, 0, (size_t)N * 4, stream);
        hipMemsetAsync(vdeg, 0, (size_t)K * 4, stream);
        hipMemsetAsync(gacc, 0, (size_t)NG * D_DIM * 4, stream);
        fb_count<<<256, 256, 0, stream>>>(dst, cnt, E);
        bucket_build<<<512, 256, 0, stream>>>(src, dst, edges_batch, nodes_batch,
                                              edge_embed, graph_ids, cnt, vdeg, bucket, E);
        int nvch = (K + VCHUNK - 1) / VCHUNK;
        spmm_kernel<<<nvch * SLICES, 512, 0, stream>>>(bucket, vdeg, node_embed, gacc, K, nvch);
        fc_kernel<<<NG, 320, 0, stream>>>(gacc, fc_w, fc_b, out);
    } else if (ws_size >= need_fb) {
        int2* elist = (int2*)(ws + off);
        hipMemsetAsync(cnt, 0, (size_t)N * 4, stream);
        hipMemsetAsync(gcnt, 0, NG * 4, stream);
        hipMemsetAsync(gacc, 0, (size_t)NG * D_DIM * 4, stream);
        count_kernel<<<256, 256, 0, stream>>>(dst, graph_ids, cnt, gcnt, E);
        scan_kernel<<<1, NG, 0, stream>>>(gcnt, goff, gfill);
        int nsb = (E + K3_EPB - 1) / K3_EPB;
        scatter_kernel<<<nsb, 256, 0, stream>>>(src, dst, edges_batch, nodes_batch, edge_embed,
                                                graph_ids, cnt, gfill, elist, E);
        int nab = (E + CH - 1) / CH;
        accum_kernel<<<nab, 320, 0, stream>>>(elist, goff, node_embed, gacc, E);
        fc_kernel<<<NG, 320, 0, stream>>>(gacc, fc_w, fc_b, out);
    }
}

// Round 6
// 254.718 us; speedup vs baseline: 3.9871x; 3.9871x over previous
//
#include <hip/hip_runtime.h>
#include <hip/hip_bf16.h>

// Problem constants (fixed by the reference):
//   N=100000, E=500000, V=50000, NE=1000000, D=300, C=20, NG=512
#define NG 512
#define D_DIM 300
#define C_DIM 20
#define NSLICE 16
#define NBINS (NSLICE * NG)   // 8192
#define CH 512                // edges per accum chunk
#define BPS 64                // blocks per slice per phase
#define SC_EPB 2048           // edges per scatter block
#define K3_EPB 2048

// lbuf transposed layout: dim d = lane*4+q stored at q*76+lane (bank-conflict-free)
#define LIDX(lane, q) ((q) * 76 + (lane))

// ---------------- K1: in-degree + (vslice,g) histogram ----------------
__global__ __launch_bounds__(1024) void count_hist(const int* __restrict__ dst,
                                                   const int* __restrict__ src,
                                                   const int* __restrict__ nodes_batch,
                                                   const int* __restrict__ graph_ids,
                                                   int* __restrict__ cnt,
                                                   int* __restrict__ kcnt,
                                                   int E, int KS) {
    __shared__ int h[NBINS];
    int t = threadIdx.x;
    for (int i = t; i < NBINS; i += 1024) h[i] = 0;
    __syncthreads();
    for (int e = blockIdx.x * 1024 + t; e < E; e += gridDim.x * 1024) {
        int d = dst[e];
        atomicAdd(&cnt[d], 1);
        int v = nodes_batch[src[e]];
        int g = graph_ids[d];
        atomicAdd(&h[(v / KS) * NG + g], 1);
    }
    __syncthreads();
    for (int i = t; i < NBINS; i += 1024)
        if (h[i]) atomicAdd(&kcnt[i], h[i]);
}

// ---------------- K2: exclusive scan of 8192 bins (single block) ----------------
__global__ __launch_bounds__(1024) void scan8k(const int* __restrict__ kcnt,
                                               int* __restrict__ koff,
                                               int* __restrict__ kfill, int E) {
    __shared__ int s[1024];
    int t = threadIdx.x;
    int loc[8];
    int sum = 0;
#pragma unroll
    for (int i = 0; i < 8; i++) { loc[i] = sum; sum += kcnt[t * 8 + i]; }
    s[t] = sum;
    __syncthreads();
    for (int off = 1; off < 1024; off <<= 1) {
        int x = (t >= off) ? s[t - off] : 0;
        __syncthreads();
        s[t] += x;
        __syncthreads();
    }
    int base = s[t] - sum;
#pragma unroll
    for (int i = 0; i < 8; i++) {
        int val = base + loc[i];
        koff[t * 8 + i] = val;
        kfill[t * 8 + i] = val;
    }
    if (t == 1023) koff[NBINS] = E;
}

// ---------------- K3: scatter edges into (vslice,g)-sorted list ----------------
__global__ __launch_bounds__(256) void scatter8k(const int* __restrict__ src,
                                                 const int* __restrict__ dst,
                                                 const int* __restrict__ eb,
                                                 const int* __restrict__ nodes_batch,
                                                 const float* __restrict__ edge_embed,
                                                 const int* __restrict__ graph_ids,
                                                 const int* __restrict__ cnt,
                                                 int* __restrict__ kfill,
                                                 int2* __restrict__ elist, int E, int KS) {
    __shared__ int bcnt[NBINS];
    __shared__ int base[NBINS];
    int t = threadIdx.x;
    int e0 = blockIdx.x * SC_EPB;
    for (int i = t; i < NBINS; i += 256) bcnt[i] = 0;
    __syncthreads();
    int vs[8];
    float scales[8];
    int keys[8];
#pragma unroll
    for (int k = 0; k < 8; k++) {
        int e = e0 + k * 256 + t;
        keys[k] = -1;
        if (e < E) {
            int d = dst[e];
            int v = nodes_batch[src[e]];
            keys[k] = (v / KS) * NG + graph_ids[d];
            vs[k] = v;
            scales[k] = edge_embed[eb[e]] / (float)max(cnt[d], 1);
            atomicAdd(&bcnt[keys[k]], 1);
        }
    }
    __syncthreads();
    for (int i = t; i < NBINS; i += 256) {
        int c = bcnt[i];
        base[i] = c ? atomicAdd(&kfill[i], c) : 0;
        bcnt[i] = 0;
    }
    __syncthreads();
#pragma unroll
    for (int k = 0; k < 8; k++) {
        if (keys[k] >= 0) {
            int pos = base[keys[k]] + atomicAdd(&bcnt[keys[k]], 1);
            elist[pos] = make_int2(vs[k], __float_as_int(scales[k]));
        }
    }
}

// ---------------- K4: sliced accumulate. phase p: slice = (bid&7)+8p on XCD bid&7 ----------------
// 640 threads = 8 edge-subgroups x 80 lanes (lane owns 4 dims, float4 gather).
__global__ __launch_bounds__(640) void accum_sliced(const int2* __restrict__ elist,
                                                    const int* __restrict__ koff,
                                                    const float* __restrict__ Bmat,
                                                    float* __restrict__ gacc, int phase) {
    __shared__ int2 tile[CH];
    __shared__ int soff[NG + 1];
    __shared__ float lbuf[4 * 76];
    int t = threadIdx.x;
    int slice = (blockIdx.x & 7) + 8 * phase;
    int j0 = blockIdx.x >> 3;   // 0..BPS-1
    for (int i = t; i <= NG; i += 640) soff[i] = koff[slice * NG + i];
    if (t < 4 * 76) lbuf[t] = 0.f;
    __syncthreads();
    int sbeg = soff[0], send = soff[NG];
    int nch = (send - sbeg + CH - 1) / CH;
    int sub = t / 80;
    int lane = t % 80;
    bool act = lane < 75;   // 75*4 = 300

    for (int cj = j0; cj < nch; cj += BPS) {
        int c0 = sbeg + cj * CH;
        int m = min(CH, send - c0);
        for (int i = t; i < m; i += 640) tile[i] = elist[c0 + i];
        __syncthreads();
        // largest bl with soff[bl] <= c0 (uniform)
        int lo = 0, hi = NG - 1;
        while (lo < hi) {
            int mid = (lo + hi + 1) >> 1;
            if (soff[mid] <= c0) lo = mid; else hi = mid - 1;
        }
        int bl = lo;
        int j = 0;
        while (j < m) {
            while (soff[bl + 1] <= c0 + j) bl++;
            int end = min(m, soff[bl + 1] - c0);
            float ax = 0.f, ay = 0.f, az = 0.f, aw = 0.f;
            if (act) {
#pragma unroll 4
                for (int jj = j + sub; jj < end; jj += 8) {
                    int2 pr = tile[jj];
                    float s = __int_as_float(pr.y);
                    float4 v = ((const float4*)(Bmat + (size_t)pr.x * D_DIM))[lane];
                    ax += s * v.x; ay += s * v.y; az += s * v.z; aw += s * v.w;
                }
                atomicAdd(&lbuf[LIDX(lane, 0)], ax);
                atomicAdd(&lbuf[LIDX(lane, 1)], ay);
                atomicAdd(&lbuf[LIDX(lane, 2)], az);
                atomicAdd(&lbuf[LIDX(lane, 3)], aw);
            }
            __syncthreads();
            if (sub == 0 && act) {
                float* dp = gacc + bl * D_DIM + lane * 4;
#pragma unroll
                for (int q = 0; q < 4; q++) {
                    float val = lbuf[LIDX(lane, q)];
                    if (val != 0.f) atomicAdd(dp + q, val);
                    lbuf[LIDX(lane, q)] = 0.f;
                }
            }
            __syncthreads();
            j = end;
        }
    }
}

// ---------------- K5: per-graph ReLU + FC ----------------
__global__ __launch_bounds__(320) void fc_kernel(const float* __restrict__ gacc,
                                                 const float* __restrict__ fc_w,
                                                 const float* __restrict__ fc_b,
                                                 float* __restrict__ out) {
    __shared__ float wlds[D_DIM * C_DIM];
    __shared__ float accs[D_DIM];
    __shared__ float outs[C_DIM];
    int gid = blockIdx.x;
    int t = threadIdx.x;
    for (int i = t; i < D_DIM * C_DIM; i += 320) wlds[i] = fc_w[i];
    if (t < D_DIM) accs[t] = gacc[gid * D_DIM + t];
    if (t < C_DIM) outs[t] = fc_b[t];
    __syncthreads();
    if (t < C_DIM * 12) {
        int c = t % C_DIM;
        int ch = t / C_DIM;
        float p = 0.f;
#pragma unroll
        for (int d = ch * 25; d < ch * 25 + 25; d++) {
            float gv = accs[d];
            gv = gv > 0.f ? gv : 0.f;
            p += gv * wlds[d * C_DIM + c];
        }
        atomicAdd(&outs[c], p);
    }
    __syncthreads();
    if (t < C_DIM) out[gid * C_DIM + t] = outs[t];
}

// ================= fallback path (R3 structure, unchanged) =================
__global__ __launch_bounds__(256) void count_kernel(const int* __restrict__ dst,
                                                    const int* __restrict__ graph_ids,
                                                    int* __restrict__ cnt,
                                                    int* __restrict__ gcnt, int E) {
    __shared__ int lg[NG];
    int t = threadIdx.x;
    for (int i = t; i < NG; i += 256) lg[i] = 0;
    __syncthreads();
    for (int e = blockIdx.x * 256 + t; e < E; e += gridDim.x * 256) {
        int d = dst[e];
        atomicAdd(&cnt[d], 1);
        atomicAdd(&lg[graph_ids[d]], 1);
    }
    __syncthreads();
    for (int i = t; i < NG; i += 256)
        if (lg[i]) atomicAdd(&gcnt[i], lg[i]);
}

__global__ __launch_bounds__(NG) void scan_kernel(const int* __restrict__ gcnt,
                                                  int* __restrict__ goff,
                                                  int* __restrict__ gfill) {
    __shared__ int s[NG];
    int t = threadIdx.x;
    int v = gcnt[t];
    s[t] = v;
    __syncthreads();
    for (int off = 1; off < NG; off <<= 1) {
        int x = (t >= off) ? s[t - off] : 0;
        __syncthreads();
        s[t] += x;
        __syncthreads();
    }
    int excl = s[t] - v;
    goff[t] = excl;
    gfill[t] = excl;
}

__global__ __launch_bounds__(256) void scatter_kernel(const int* __restrict__ src,
                                                      const int* __restrict__ dst,
                                                      const int* __restrict__ eb,
                                                      const int* __restrict__ nodes_batch,
                                                      const float* __restrict__ edge_embed,
                                                      const int* __restrict__ graph_ids,
                                                      const int* __restrict__ cnt,
                                                      int* __restrict__ gfill,
                                                      int2* __restrict__ elist, int E) {
    __shared__ int bcnt[NG];
    __shared__ int base[NG];
    int t = threadIdx.x;
    int e0 = blockIdx.x * K3_EPB;
    for (int i = t; i < NG; i += 256) bcnt[i] = 0;
    __syncthreads();
    int rows[8];
    float scales[8];
    int gids[8];
#pragma unroll
    for (int k = 0; k < 8; k++) {
        int e = e0 + k * 256 + t;
        gids[k] = -1;
        if (e < E) {
            int d = dst[e];
            int g = graph_ids[d];
            gids[k] = g;
            rows[k] = nodes_batch[src[e]];
            scales[k] = edge_embed[eb[e]] / (float)max(cnt[d], 1);
            atomicAdd(&bcnt[g], 1);
        }
    }
    __syncthreads();
    for (int i = t; i < NG; i += 256) {
        int c2 = bcnt[i];
        base[i] = c2 ? atomicAdd(&gfill[i], c2) : 0;
        bcnt[i] = 0;
    }
    __syncthreads();
#pragma unroll
    for (int k = 0; k < 8; k++) {
        int g = gids[k];
        if (g >= 0) {
            int pos = base[g] + atomicAdd(&bcnt[g], 1);
            elist[pos] = make_int2(rows[k], __float_as_int(scales[k]));
        }
    }
}

__global__ __launch_bounds__(320) void accum_kernel(const int2* __restrict__ elist,
                                                    const int* __restrict__ goff,
                                                    const float* __restrict__ node_embed,
                                                    float* __restrict__ gacc, int E) {
    __shared__ int2 tile[256];
    __shared__ int goff_s[NG + 1];
    int t = threadIdx.x;
    int sub = t / 80;
    int lane = t % 80;
    int d0 = lane * 4;
    bool act = d0 < D_DIM;
    int pos0 = blockIdx.x * 256;
    int m = min(256, E - pos0);
    for (int i = t; i < NG; i += 320) goff_s[i] = goff[i];
    if (t == 0) goff_s[NG] = E;
    for (int i = t; i < m; i += 320) tile[i] = elist[pos0 + i];
    __syncthreads();
    int lo = 0, hi = NG - 1;
    while (lo < hi) {
        int mid = (lo + hi + 1) >> 1;
        if (goff_s[mid] <= pos0) lo = mid; else hi = mid - 1;
    }
    int g = lo;
    int j = 0;
    while (j < m) {
        while (pos0 + j >= goff_s[g + 1]) g++;
        int end = min(m, goff_s[g + 1] - pos0);
        float ax = 0.f, ay = 0.f, az = 0.f, aw = 0.f;
        if (act) {
#pragma unroll 8
            for (int jj = j + sub; jj < end; jj += 4) {
                int2 pr = tile[jj];
                float s = __int_as_float(pr.y);
                const float4* rowp = (const float4*)(node_embed + (size_t)pr.x * D_DIM);
                float4 vv = rowp[lane];
                ax += s * vv.x; ay += s * vv.y; az += s * vv.z; aw += s * vv.w;
            }
            float* dest = gacc + g * D_DIM + d0;
            atomicAdd(dest + 0, ax);
            atomicAdd(dest + 1, ay);
            atomicAdd(dest + 2, az);
            atomicAdd(dest + 3, aw);
        }
        j = end;
    }
}

extern "C" void kernel_launch(void* const* d_in, const int* in_sizes, int n_in,
                              void* d_out, int out_size, void* d_ws, size_t ws_size,
                              hipStream_t stream) {
    const int* nodes_batch = (const int*)d_in[0];
    const int* edges_batch = (const int*)d_in[1];
    const int* src = (const int*)d_in[2];
    const int* dst = (const int*)d_in[3];
    const int* graph_ids = (const int*)d_in[4];
    const float* node_embed = (const float*)d_in[5];
    const float* edge_embed = (const float*)d_in[6];
    const float* fc_w = (const float*)d_in[7];
    const float* fc_b = (const float*)d_in[8];
    float* out = (float*)d_out;

    int N = in_sizes[0];
    int E = in_sizes[2];
    int K = in_sizes[5] / D_DIM;   // vocab size V
    int KS = (K + NSLICE - 1) / NSLICE;

    char* ws = (char*)d_ws;
    size_t off = 0;
    int* cnt = (int*)(ws + off); off += (size_t)N * 4;
    int* kcnt = (int*)(ws + off); off += (size_t)NBINS * 4;
    int* koff = (int*)(ws + off); off += (size_t)(NBINS + 1) * 4;
    int* kfill = (int*)(ws + off); off += (size_t)NBINS * 4;
    int* gcnt = (int*)(ws + off); off += NG * 4;
    int* goff = (int*)(ws + off); off += NG * 4;
    int* gfill = (int*)(ws + off); off += NG * 4;
    float* gacc = (float*)(ws + off); off += (size_t)NG * D_DIM * 4;
    off = (off + 15) & ~(size_t)15;
    size_t need = off + (size_t)E * 8;

    if (ws_size >= need) {
        int2* elist = (int2*)(ws + off);
        hipMemsetAsync(cnt, 0, (size_t)N * 4, stream);
        hipMemsetAsync(kcnt, 0, (size_t)NBINS * 4, stream);
        hipMemsetAsync(gacc, 0, (size_t)NG * D_DIM * 4, stream);
        count_hist<<<64, 1024, 0, stream>>>(dst, src, nodes_batch, graph_ids, cnt, kcnt, E, KS);
        scan8k<<<1, 1024, 0, stream>>>(kcnt, koff, kfill, E);
        int nsb = (E + SC_EPB - 1) / SC_EPB;
        scatter8k<<<nsb, 256, 0, stream>>>(src, dst, edges_batch, nodes_batch, edge_embed,
                                           graph_ids, cnt, kfill, elist, E, KS);
        accum_sliced<<<8 * BPS, 640, 0, stream>>>(elist, koff, node_embed, gacc, 0);
        accum_sliced<<<8 * BPS, 640, 0, stream>>>(elist, koff, node_embed, gacc, 1);
        fc_kernel<<<NG, 320, 0, stream>>>(gacc, fc_w, fc_b, out);
    }
}